// Round 3
// baseline (689.355 us; speedup 1.0000x reference)
//
#include <hip/hip_runtime.h>
#include <stdint.h>

// GeneDynamics: out = -x + (A @ x^2) / (x^2 + 1)
// A: [16384,16384] fp32 (1.07 GB, streamed once). HBM floor ~171us.
// v3: xh via uniform global loads (no LDS), A staged via global_load_lds width-4
//     with XOR-swizzled source (lane-linear LDS dest, conflict-free reads).

#define NN 16384
#define DIM 16
#define RB 512                 // rows per block
#define TPB 256
#define KSPLIT 32
#define KRANGE (NN / KSPLIT)   // 512
#define KC 16                  // K per LDS chunk
#define NRB (NN / RB)          // 32 row-blocks
#define NCHUNK (KRANGE / KC)   // 32

__global__ __launch_bounds__(256) void init_out_kernel(const float* __restrict__ x,
                                                       float* __restrict__ out) {
    int i = blockIdx.x * 256 + threadIdx.x;           // 65536 float4s
    float4 v = reinterpret_cast<const float4*>(x)[i];
    reinterpret_cast<float4*>(out)[i] = make_float4(-v.x, -v.y, -v.z, -v.w);
}

__device__ __forceinline__ void gload_lds4(const float* g, float* l) {
    __builtin_amdgcn_global_load_lds(
        (const __attribute__((address_space(1))) void*)g,
        (__attribute__((address_space(3))) void*)l, 4, 0, 0);
}

__global__ __launch_bounds__(TPB, 4) void agg_kernel(const float* __restrict__ A,
                                                     const float* __restrict__ x,
                                                     float* __restrict__ out) {
    // swizzled A tile: LDS[row*16 + j] = A[r0+row][k0+c + (j ^ s(row))],
    // s(row) = (row&15) ^ ((row>>4)&3). Read element k at j = k ^ s(row):
    // bank = 16*(row&1) + (k^s(row)) -> exactly 2 lanes/bank over 64 rows (free).
    __shared__ float a_t[RB * KC];   // 32 KiB

    const int tid = threadIdx.x;
    const int rb  = blockIdx.x & (NRB - 1);
    const int ks  = blockIdx.x / NRB;
    const int r0  = rb * RB;
    const int k0  = ks * KRANGE;

    // ---- staging decomposition: call i covers LDS floats [i*256, i*256+256) ----
    // lane l of wave w writes LDS index i*256 + w*64 + l  (HW: base + lane*4B)
    //   -> row = i*16 + rl,  j = jl   with rl = w*4 + (l>>4), jl = l&15
    // source element = A[r0 + i*16 + rl][k0 + c + (jl ^ rl ^ (i&3))]
    //   (since s(i*16+rl) = rl ^ (i&3) for rl<16)
    const int l  = tid & 63;
    const int w  = tid >> 6;
    const int rl = (w << 2) + (l >> 4);   // 0..15
    const int jl = l & 15;

    const float* gbase = A + (size_t)r0 * NN + k0;     // uniform
    size_t toff[4];
    #pragma unroll
    for (int v = 0; v < 4; ++v)
        toff[v] = (size_t)rl * NN + (size_t)(jl ^ rl ^ v);   // per-thread, i&3 variants
    float* lbase = a_t + w * 64;                        // wave-uniform

    // ---- compute-side addressing ----
    const int sthr = (tid & 15) ^ ((tid >> 4) & 3);     // s(tid) == s(tid+256)
    const float* abase0 = a_t + (tid << 4);
    const float* abase1 = a_t + ((tid + 256) << 4);

    float4 acc0[4], acc1[4];
    #pragma unroll
    for (int v = 0; v < 4; ++v) {
        acc0[v] = make_float4(0.f, 0.f, 0.f, 0.f);
        acc1[v] = make_float4(0.f, 0.f, 0.f, 0.f);
    }

    for (int t = 0; t < NCHUNK; ++t) {
        const int c = t * KC;
        __syncthreads();                 // prev chunk's reads done before overwrite
        #pragma unroll
        for (int i = 0; i < 32; ++i) {
            gload_lds4(gbase + (size_t)(i * 16) * NN + c + toff[i & 3],
                       lbase + i * 256);
        }
        __syncthreads();                 // barrier drain (vmcnt(0)) -> tile resident

        const float* xc = x + (size_t)(k0 + c) * DIM;   // uniform address stream
        #pragma unroll
        for (int k = 0; k < KC; ++k) {
            float a0 = abase0[k ^ sthr];
            float a1 = abase1[k ^ sthr];
            const float4* xr = reinterpret_cast<const float4*>(xc + k * DIM);
            #pragma unroll
            for (int v = 0; v < 4; ++v) {
                float4 xv = xr[v];
                float qx = xv.x * xv.x, qy = xv.y * xv.y,
                      qz = xv.z * xv.z, qw = xv.w * xv.w;
                acc0[v].x += a0 * qx; acc0[v].y += a0 * qy;
                acc0[v].z += a0 * qz; acc0[v].w += a0 * qw;
                acc1[v].x += a1 * qx; acc1[v].y += a1 * qy;
                acc1[v].z += a1 * qz; acc1[v].w += a1 * qw;
            }
        }
    }

    // ---- epilogue: out += partial_agg / (x^2 + 1)  (linear in agg -> split-K safe) ----
    #pragma unroll
    for (int h = 0; h < 2; ++h) {
        int r = r0 + tid + h * 256;
        const float4* xr4 = reinterpret_cast<const float4*>(x + (size_t)r * DIM);
        float* orow = out + (size_t)r * DIM;
        #pragma unroll
        for (int v = 0; v < 4; ++v) {
            float4 xv = xr4[v];
            float4 a = h ? acc1[v] : acc0[v];
            atomicAdd(&orow[(v << 2) + 0], a.x / (xv.x * xv.x + 1.0f));
            atomicAdd(&orow[(v << 2) + 1], a.y / (xv.y * xv.y + 1.0f));
            atomicAdd(&orow[(v << 2) + 2], a.z / (xv.z * xv.z + 1.0f));
            atomicAdd(&orow[(v << 2) + 3], a.w / (xv.w * xv.w + 1.0f));
        }
    }
}

extern "C" void kernel_launch(void* const* d_in, const int* in_sizes, int n_in,
                              void* d_out, int out_size, void* d_ws, size_t ws_size,
                              hipStream_t stream) {
    const float* A = (const float*)d_in[0];
    const float* x = (const float*)d_in[1];
    float* out = (float*)d_out;

    init_out_kernel<<<(NN * DIM / 4) / 256, 256, 0, stream>>>(x, out);
    agg_kernel<<<NRB * KSPLIT, TPB, 0, stream>>>(A, x, out);
}

// Round 4
// 439.092 us; speedup vs baseline: 1.5700x; 1.5700x over previous
//
#include <hip/hip_runtime.h>
#include <stdint.h>

// GeneDynamics: out = -x + (A @ x^2) / (x^2 + 1)
// A: [16384,16384] fp32, streamed once -> HBM-bound, floor ~171us.
// v4: wave-private dbuf pipeline, width-16 global_load_lds with float4-XOR
//     swizzled source, counted vmcnt(4), ZERO barriers in k-loop.
//     xh = x^2 and inv = 1/(x^2+1) precomputed into d_ws.

#define NN 16384
#define DIM 16
#define TPB 256
#define WROWS 64               // rows per wave (1 row / lane)
#define BROWS 256              // rows per block (4 waves)
#define NRB (NN / BROWS)       // 64 row-blocks
#define KSPLIT 16
#define KRANGE (NN / KSPLIT)   // 1024
#define KC 16                  // k per chunk
#define NCH (KRANGE / KC)      // 64 chunks

// prep: out = -x ; xh = x^2 ; inv = 1/(x^2+1)
__global__ __launch_bounds__(256) void prep_kernel(const float* __restrict__ x,
                                                   float* __restrict__ out,
                                                   float* __restrict__ xh,
                                                   float* __restrict__ inv) {
    int i = blockIdx.x * 256 + threadIdx.x;            // 65536 float4s
    float4 v = reinterpret_cast<const float4*>(x)[i];
    reinterpret_cast<float4*>(out)[i] = make_float4(-v.x, -v.y, -v.z, -v.w);
    float4 h = make_float4(v.x * v.x, v.y * v.y, v.z * v.z, v.w * v.w);
    reinterpret_cast<float4*>(xh)[i] = h;
    reinterpret_cast<float4*>(inv)[i] =
        make_float4(1.0f / (h.x + 1.0f), 1.0f / (h.y + 1.0f),
                    1.0f / (h.z + 1.0f), 1.0f / (h.w + 1.0f));
}

__device__ __forceinline__ void gload_lds16(const float* g, float* l) {
    __builtin_amdgcn_global_load_lds(
        (const __attribute__((address_space(1))) void*)g,
        (__attribute__((address_space(3))) void*)l, 16, 0, 0);
}

__global__ __launch_bounds__(TPB) void agg_kernel(const float* __restrict__ A,
                                                  const float* __restrict__ xh,
                                                  const float* __restrict__ inv,
                                                  float* __restrict__ out) {
    // wave-private tile: 64 rows x 16 k, float4-slot XOR swizzle s4(row)=(row>>1)&3.
    // slot (row, v) holds A[row][chunk + 4*(v ^ s4(row)) .. +3]; read of k-group g
    // at slot g ^ s4(row) -> start banks spread 2-way over each 16-lane phase (free).
    __shared__ float lds[2][4][WROWS * KC];   // 2 bufs x 4 waves x 4KiB = 32 KiB

    const int tid = threadIdx.x;
    const int l   = tid & 63;
    const int w   = tid >> 6;
    const int rb  = blockIdx.x & (NRB - 1);   // 0..63
    const int ks  = blockIdx.x >> 6;          // 0..15 (wait: NRB=64 -> bid = ks*64+rb)
    const int r0  = rb * BROWS + w * WROWS;   // wave's first row
    const size_t k0 = (size_t)ks * KRANGE;

    // staging source offsets: instr i, lane l -> LDS float4-slot i*64+l
    //   row_s = i*16 + (l>>2), vs = l&3, src col = 4*(vs ^ s4(row_s))
    size_t soff[4];
    #pragma unroll
    for (int i = 0; i < 4; ++i) {
        int row_s = i * 16 + (l >> 2);
        int col = 4 * ((l & 3) ^ ((row_s >> 1) & 3));
        soff[i] = (size_t)(r0 + row_s) * NN + (size_t)col;
    }
    const float* Ak = A + k0;

    float4 acc[4];
    #pragma unroll
    for (int v = 0; v < 4; ++v) acc[v] = make_float4(0.f, 0.f, 0.f, 0.f);

    const int s4 = (l >> 1) & 3;

    // ---- prologue: stage chunk 0 into buf 0 ----
    #pragma unroll
    for (int i = 0; i < 4; ++i)
        gload_lds16(Ak + soff[i], &lds[0][w][i * 256]);

    int cur = 0;
    for (int t = 0; t < NCH - 1; ++t) {
        // issue next chunk into other buffer (stays in flight across compute)
        {
            const float* src = Ak + (size_t)(t + 1) * KC;
            float* dst = &lds[cur ^ 1][w][0];
            #pragma unroll
            for (int i = 0; i < 4; ++i)
                gload_lds16(src + soff[i], dst + i * 256);
        }
        // wait for chunk t's 4 loads only (keep next 4 in flight)
        asm volatile("s_waitcnt vmcnt(4)" ::: "memory");
        __builtin_amdgcn_sched_barrier(0);

        // ---- compute chunk t from buf cur ----
        {
            const float* row = &lds[cur][w][l * KC];
            float4 fr[4];
            #pragma unroll
            for (int g = 0; g < 4; ++g)
                fr[g] = *reinterpret_cast<const float4*>(&row[4 * (g ^ s4)]);
            const float4* xq = reinterpret_cast<const float4*>(
                xh + (k0 + (size_t)t * KC) * DIM);
            #pragma unroll
            for (int k = 0; k < KC; ++k) {
                float a = reinterpret_cast<const float*>(&fr[k >> 2])[k & 3];
                #pragma unroll
                for (int v = 0; v < 4; ++v) {
                    float4 q = xq[k * 4 + v];
                    acc[v].x += a * q.x; acc[v].y += a * q.y;
                    acc[v].z += a * q.z; acc[v].w += a * q.w;
                }
            }
        }
        // all ds_reads of buf done before it is re-staged next iteration
        asm volatile("s_waitcnt lgkmcnt(0)" ::: "memory");
        cur ^= 1;
    }

    // ---- epilogue chunk (no prefetch): drain all staging loads ----
    asm volatile("s_waitcnt vmcnt(0)" ::: "memory");
    __builtin_amdgcn_sched_barrier(0);
    {
        const float* row = &lds[cur][w][l * KC];
        float4 fr[4];
        #pragma unroll
        for (int g = 0; g < 4; ++g)
            fr[g] = *reinterpret_cast<const float4*>(&row[4 * (g ^ s4)]);
        const float4* xq = reinterpret_cast<const float4*>(
            xh + (k0 + (size_t)(NCH - 1) * KC) * DIM);
        #pragma unroll
        for (int k = 0; k < KC; ++k) {
            float a = reinterpret_cast<const float*>(&fr[k >> 2])[k & 3];
            #pragma unroll
            for (int v = 0; v < 4; ++v) {
                float4 q = xq[k * 4 + v];
                acc[v].x += a * q.x; acc[v].y += a * q.y;
                acc[v].z += a * q.z; acc[v].w += a * q.w;
            }
        }
    }

    // ---- out += partial * inv  (split-K safe: epilogue linear in agg) ----
    const int r = r0 + l;
    const float4* iv4 = reinterpret_cast<const float4*>(inv + (size_t)r * DIM);
    float* orow = out + (size_t)r * DIM;
    #pragma unroll
    for (int v = 0; v < 4; ++v) {
        float4 iv = iv4[v];
        atomicAdd(&orow[4 * v + 0], acc[v].x * iv.x);
        atomicAdd(&orow[4 * v + 1], acc[v].y * iv.y);
        atomicAdd(&orow[4 * v + 2], acc[v].z * iv.z);
        atomicAdd(&orow[4 * v + 3], acc[v].w * iv.w);
    }
}

extern "C" void kernel_launch(void* const* d_in, const int* in_sizes, int n_in,
                              void* d_out, int out_size, void* d_ws, size_t ws_size,
                              hipStream_t stream) {
    const float* A = (const float*)d_in[0];
    const float* x = (const float*)d_in[1];
    float* out = (float*)d_out;
    float* xh  = (float*)d_ws;                 // 1 MiB
    float* inv = (float*)d_ws + (size_t)NN * DIM;  // 1 MiB

    prep_kernel<<<(NN * DIM / 4) / 256, 256, 0, stream>>>(x, out, xh, inv);
    agg_kernel<<<NRB * KSPLIT, TPB, 0, stream>>>(A, xh, inv, out);
}

// Round 5
// 398.658 us; speedup vs baseline: 1.7292x; 1.1014x over previous
//
#include <hip/hip_runtime.h>
#include <stdint.h>

// GeneDynamics: out = -x + (A @ x^2) / (x^2 + 1)
// v5: compute phase issues ZERO vmem (xh staged in LDS) so the counted
//     vmcnt(10) is the only VMEM wait -> prefetch truly stays in flight.
//     4 rows/lane with in-wave k-split; shfl_xor butterfly merge.

#define NN 16384
#define DIM 16
#define TPB 128                // 2 waves
#define NWAVES 2
#define WROWS 64               // rows per wave
#define BROWS 128              // rows per block
#define NRB 128                // NN / BROWS
#define KSPLIT 16
#define KRANGE 1024            // NN / KSPLIT
#define KC 32                  // k per chunk (128 B per row per chunk)
#define NCH 32                 // KRANGE / KC

// prep: out = -x ; xh = x^2 ; inv = 1/(x^2+1)
__global__ __launch_bounds__(256) void prep_kernel(const float* __restrict__ x,
                                                   float* __restrict__ out,
                                                   float* __restrict__ xh,
                                                   float* __restrict__ inv) {
    int i = blockIdx.x * 256 + threadIdx.x;            // 65536 float4s
    float4 v = reinterpret_cast<const float4*>(x)[i];
    reinterpret_cast<float4*>(out)[i] = make_float4(-v.x, -v.y, -v.z, -v.w);
    float4 h = make_float4(v.x * v.x, v.y * v.y, v.z * v.z, v.w * v.w);
    reinterpret_cast<float4*>(xh)[i] = h;
    reinterpret_cast<float4*>(inv)[i] =
        make_float4(1.0f / (h.x + 1.0f), 1.0f / (h.y + 1.0f),
                    1.0f / (h.z + 1.0f), 1.0f / (h.w + 1.0f));
}

__device__ __forceinline__ void gload_lds16(const float* g, float* l) {
    __builtin_amdgcn_global_load_lds(
        (const __attribute__((address_space(1))) void*)g,
        (__attribute__((address_space(3))) void*)l, 16, 0, 0);
}

__global__ __launch_bounds__(TPB) void agg_kernel(const float* __restrict__ A,
                                                  const float* __restrict__ xh,
                                                  const float* __restrict__ inv,
                                                  float* __restrict__ out) {
    // A tile per wave: 64 rows x 32 k. Row r stores logical float4-slot s at
    // physical slot s^(r&7)  (involution; staged via pre-swizzled global src).
    // xh tile per wave: 32 k x 16 dim = 128 float4-slots; logical L at L^(L>>5).
    __shared__ float ldsA[2][NWAVES][WROWS * KC];   // 32 KiB
    __shared__ float ldsX[2][NWAVES][KC * DIM];     // 8 KiB

    const int tid = threadIdx.x;
    const int l   = tid & 63;
    const int w   = tid >> 6;
    const int rb  = blockIdx.x & (NRB - 1);
    const int ks  = blockIdx.x >> 7;
    const int r0w = rb * BROWS + w * WROWS;
    const size_t k0 = (size_t)ks * KRANGE;

    const int l7 = l & 7, lo3 = l >> 3, q = l >> 4, m = l & 15;

    // A staging: instr i, lane l -> LDS f4-slot i*64+l = row(i*8+lo3), phys(l7)
    //   -> logical slot l7^lo3 of that row (row&7 == lo3)
    const float* Abase = A + (size_t)(r0w + lo3) * NN + (size_t)(4 * (l7 ^ lo3)) + k0;
    // xh staging: instr j, lane l -> pos p=j*64+l holds logical p^((p>>5)&7)
    int xo0, xo1;
    { int p0 = l;      xo0 = 4 * (p0 ^ ((p0 >> 5) & 7)); }
    { int p1 = 64 + l; xo1 = 4 * (p1 ^ ((p1 >> 5) & 7)); }
    const float* Xbase = xh + k0 * DIM;

    float4 acc[4][4];
    #pragma unroll
    for (int j = 0; j < 4; ++j)
        #pragma unroll
        for (int v = 0; v < 4; ++v) acc[j][v] = make_float4(0.f, 0.f, 0.f, 0.f);

#define STAGE(T, B)                                                          \
    {                                                                        \
        const float* sA = Abase + (size_t)(T) * KC;                          \
        float* dA = &ldsA[B][w][0];                                          \
        _Pragma("unroll")                                                    \
        for (int i = 0; i < 8; ++i)                                          \
            gload_lds16(sA + (size_t)(i * 8) * NN, dA + i * 256);            \
        const float* sX = Xbase + (size_t)(T) * (KC * DIM);                  \
        float* dX = &ldsX[B][w][0];                                          \
        gload_lds16(sX + xo0, dX);                                           \
        gload_lds16(sX + xo1, dX + 256);                                     \
    }

#define COMPUTE(B)                                                           \
    {                                                                        \
        const float* wA = &ldsA[B][w][0];                                    \
        const float* wX = &ldsX[B][w][0];                                    \
        float4 fr[4][2];                                                     \
        const float* pA0 = wA + m * 32 + 4 * ((2 * q) ^ l7);                 \
        const float* pA1 = wA + m * 32 + 4 * ((2 * q + 1) ^ l7);             \
        _Pragma("unroll")                                                    \
        for (int j = 0; j < 4; ++j) {                                        \
            fr[j][0] = *reinterpret_cast<const float4*>(pA0 + j * 512);      \
            fr[j][1] = *reinterpret_cast<const float4*>(pA1 + j * 512);      \
        }                                                                    \
        const float* px0 = wX + 128 * q + 4 * (0 ^ q);                       \
        const float* px1 = wX + 128 * q + 4 * (1 ^ q);                       \
        const float* px2 = wX + 128 * q + 4 * (2 ^ q);                       \
        const float* px3 = wX + 128 * q + 4 * (3 ^ q);                       \
        _Pragma("unroll")                                                    \
        for (int kk = 0; kk < 8; ++kk) {                                     \
            float4 x0 = *reinterpret_cast<const float4*>(px0 + 16 * kk);     \
            float4 x1 = *reinterpret_cast<const float4*>(px1 + 16 * kk);     \
            float4 x2 = *reinterpret_cast<const float4*>(px2 + 16 * kk);     \
            float4 x3 = *reinterpret_cast<const float4*>(px3 + 16 * kk);     \
            _Pragma("unroll")                                                \
            for (int j = 0; j < 4; ++j) {                                    \
                float a = reinterpret_cast<const float*>(&fr[j][kk >> 2])[kk & 3]; \
                acc[j][0].x += a * x0.x; acc[j][0].y += a * x0.y;            \
                acc[j][0].z += a * x0.z; acc[j][0].w += a * x0.w;            \
                acc[j][1].x += a * x1.x; acc[j][1].y += a * x1.y;            \
                acc[j][1].z += a * x1.z; acc[j][1].w += a * x1.w;            \
                acc[j][2].x += a * x2.x; acc[j][2].y += a * x2.y;            \
                acc[j][2].z += a * x2.z; acc[j][2].w += a * x2.w;            \
                acc[j][3].x += a * x3.x; acc[j][3].y += a * x3.y;            \
                acc[j][3].z += a * x3.z; acc[j][3].w += a * x3.w;            \
            }                                                                \
        }                                                                    \
    }

    // prologue
    STAGE(0, 0);

    for (int t = 0; t < NCH - 1; ++t) {
        // buffer (t+1)&1's previous reads (chunk t-1) must be done
        asm volatile("s_waitcnt lgkmcnt(0)" ::: "memory");
        __builtin_amdgcn_sched_barrier(0);
        STAGE(t + 1, (t + 1) & 1);
        // wait chunk t's 10 loads; keep t+1's 10 in flight (in-order retire)
        asm volatile("s_waitcnt vmcnt(10)" ::: "memory");
        __builtin_amdgcn_sched_barrier(0);
        COMPUTE(t & 1);
    }
    asm volatile("s_waitcnt vmcnt(0)" ::: "memory");
    __builtin_amdgcn_sched_barrier(0);
    COMPUTE((NCH - 1) & 1);

    // ---- merge k-quarters: butterfly over lane bits 4,5 ----
    #pragma unroll
    for (int j = 0; j < 4; ++j)
        #pragma unroll
        for (int v = 0; v < 4; ++v) {
            acc[j][v].x += __shfl_xor(acc[j][v].x, 16);
            acc[j][v].y += __shfl_xor(acc[j][v].y, 16);
            acc[j][v].z += __shfl_xor(acc[j][v].z, 16);
            acc[j][v].w += __shfl_xor(acc[j][v].w, 16);
        }
    #pragma unroll
    for (int j = 0; j < 4; ++j)
        #pragma unroll
        for (int v = 0; v < 4; ++v) {
            acc[j][v].x += __shfl_xor(acc[j][v].x, 32);
            acc[j][v].y += __shfl_xor(acc[j][v].y, 32);
            acc[j][v].z += __shfl_xor(acc[j][v].z, 32);
            acc[j][v].w += __shfl_xor(acc[j][v].w, 32);
        }

    // lane writes row m + 16*q (static acc index per branch — rule #20)
    float4 o0, o1, o2, o3;
    if (q == 0)      { o0 = acc[0][0]; o1 = acc[0][1]; o2 = acc[0][2]; o3 = acc[0][3]; }
    else if (q == 1) { o0 = acc[1][0]; o1 = acc[1][1]; o2 = acc[1][2]; o3 = acc[1][3]; }
    else if (q == 2) { o0 = acc[2][0]; o1 = acc[2][1]; o2 = acc[2][2]; o3 = acc[2][3]; }
    else             { o0 = acc[3][0]; o1 = acc[3][1]; o2 = acc[3][2]; o3 = acc[3][3]; }

    const int R = r0w + m + 16 * q;
    const float* ivp = inv + (size_t)R * DIM;
    float* orow = out + (size_t)R * DIM;
    {
        float4 iv = *reinterpret_cast<const float4*>(ivp + 0);
        atomicAdd(&orow[0], o0.x * iv.x); atomicAdd(&orow[1], o0.y * iv.y);
        atomicAdd(&orow[2], o0.z * iv.z); atomicAdd(&orow[3], o0.w * iv.w);
    }
    {
        float4 iv = *reinterpret_cast<const float4*>(ivp + 4);
        atomicAdd(&orow[4], o1.x * iv.x); atomicAdd(&orow[5], o1.y * iv.y);
        atomicAdd(&orow[6], o1.z * iv.z); atomicAdd(&orow[7], o1.w * iv.w);
    }
    {
        float4 iv = *reinterpret_cast<const float4*>(ivp + 8);
        atomicAdd(&orow[8],  o2.x * iv.x); atomicAdd(&orow[9],  o2.y * iv.y);
        atomicAdd(&orow[10], o2.z * iv.z); atomicAdd(&orow[11], o2.w * iv.w);
    }
    {
        float4 iv = *reinterpret_cast<const float4*>(ivp + 12);
        atomicAdd(&orow[12], o3.x * iv.x); atomicAdd(&orow[13], o3.y * iv.y);
        atomicAdd(&orow[14], o3.z * iv.z); atomicAdd(&orow[15], o3.w * iv.w);
    }
#undef STAGE
#undef COMPUTE
}

extern "C" void kernel_launch(void* const* d_in, const int* in_sizes, int n_in,
                              void* d_out, int out_size, void* d_ws, size_t ws_size,
                              hipStream_t stream) {
    const float* A = (const float*)d_in[0];
    const float* x = (const float*)d_in[1];
    float* out = (float*)d_out;
    float* xhp = (float*)d_ws;                      // 1 MiB
    float* inv = (float*)d_ws + (size_t)NN * DIM;   // 1 MiB

    prep_kernel<<<(NN * DIM / 4) / 256, 256, 0, stream>>>(x, out, xhp, inv);
    agg_kernel<<<NRB * KSPLIT, TPB, 0, stream>>>(A, xhp, inv, out);
}